// Round 18
// baseline (259.753 us; speedup 1.0000x reference)
//
#include <hip/hip_runtime.h>
#include <hip/hip_bf16.h>

// ---- problem constants ----
#define OUT_CH   31
#define COEF_LEN 7688                 // 31*31*8
#define NPIX     16384                // 128*128
#define CHUNKS   31                   // KAN input channels (independent param groups)
#define NFRG     24                   // param fragments per chunk (384 padded M rows)
#define NR       9                    // K-steps: r = ky*3+kx; k-in-step = conv channel ci
#define FRAG_U16 512                  // u16 per fragment (64 lanes x 8)
#define STEP_U16 (NFRG*FRAG_U16)      // 12288 u16 per (chunk,r) step
#define BP3_B    ((size_t)CHUNKS*NR*STEP_U16*2)        // 6,856,704
#define P1_B     ((size_t)OUT_CH*NPIX*4)               // 2,031,616
#define WS_NEED  (BP3_B + P1_B)                        // 8,888,320

using f32x4 = __attribute__((ext_vector_type(4))) float;
using s16x8 = __attribute__((ext_vector_type(8))) short;

__device__ __forceinline__ unsigned short f2bf(float f) {
    unsigned int u = __float_as_uint(f);
    unsigned int r = (u + 0x7FFFu + ((u >> 16) & 1u)) >> 16;
    return (unsigned short)r;
}

// ---------------------------------------------------------------------------
// Pack gen_w/gen_b into bf16 A-fragment layout (R14-proven, unchanged).
// Bias folded into GEMM: slab slot 31 = 1.0; A[ci=31] at r==4 carries gb[p].
//  bp3[i][r][f][lane][8] bf16.  M-row m = lane&15; k-in-step ci = (lane>>4)*8+jj.
//  param identity: o = (m>>2)*8 + f/3, jslot = (f%3)*4 + (m&3)
//    jslot 0..7 = coef j, 8 = univ, 9 = res, 10..11 = zero pad
// ---------------------------------------------------------------------------
__global__ void pack_kernel(const float* __restrict__ gw, const float* __restrict__ gb,
                            unsigned short* __restrict__ bp) {
    const int NMAIN = CHUNKS * NFRG * 64;          // 47616
    int tt = blockIdx.x * 256 + threadIdx.x;
    if (tt >= NMAIN) return;
    int lane = tt & 63;
    int u = tt >> 6;
    int f = u % NFRG;
    int i = u / NFRG;
    int m = lane & 15, q8 = lane >> 4;
    int o = (m >> 2) * 8 + f / 3;
    int jslot = (f % 3) * 4 + (m & 3);
    int p = -1;
    if (o < OUT_CH && jslot < 10) {
        if (jslot < 8)       p = i * 248 + o * 8 + jslot;
        else if (jslot == 8) p = COEF_LEN + i * 31 + o;
        else                 p = COEF_LEN + 961 + i * 31 + o;
    }
    s16x8 vr[NR];
    #pragma unroll
    for (int r = 0; r < NR; ++r)
        #pragma unroll
        for (int jj = 0; jj < 8; ++jj) vr[r][jj] = 0;
    #pragma unroll
    for (int jj = 0; jj < 8; ++jj) {
        int ci = q8 * 8 + jj;
        if (p >= 0) {
            if (ci < 31) {
                const float* gr = gw + (long)p * 279 + ci * 9;
                #pragma unroll
                for (int r = 0; r < NR; ++r) vr[r][jj] = (short)f2bf(gr[r]);
            } else {
                vr[4][jj] = (short)f2bf(gb[p]);   // bias channel, center tap only
            }
        }
    }
    #pragma unroll
    for (int r = 0; r < NR; ++r)
        *reinterpret_cast<s16x8*>(bp + (((size_t)i * NR + r) * NFRG + f) * FRAG_U16 + lane * 8) = vr[r];
}

// step-body macros (compile-time indices only; NO lambdas — R15's spill cause)
#define KAN_ZERO()                                                            \
    _Pragma("unroll") for (int fl = 0; fl < 3; ++fl)                          \
        _Pragma("unroll") for (int pg = 0; pg < 4; ++pg)                      \
            acc[fl][pg] = (f32x4){0.f, 0.f, 0.f, 0.f};

#define KAN_MFMA(BUF)                                                         \
    {                                                                         \
        const int roff = ((r / 3) * 66 + (r % 3)) * 80;                       \
        s16x8 pbv[4];                                                         \
        _Pragma("unroll") for (int pg = 0; pg < 4; ++pg)                      \
            pbv[pg] = *reinterpret_cast<const s16x8*>(slabb + sa[pg] + roff); \
        __builtin_amdgcn_s_setprio(1);                                        \
        _Pragma("unroll") for (int fl = 0; fl < 3; ++fl)                      \
            _Pragma("unroll") for (int pg = 0; pg < 4; ++pg)                  \
                acc[fl][pg] = __builtin_amdgcn_mfma_f32_16x16x32_bf16(        \
                    pa[BUF][fl], pbv[pg], acc[fl][pg], 0, 0, 0);              \
        __builtin_amdgcn_s_setprio(0);                                        \
    }

#define KAN_EPI(KK)                                                           \
    _Pragma("unroll") for (int pg = 0; pg < 4; ++pg) {                        \
        const float* wr = Wt + (pg * 16 + pix16) * 132 + (KK) * 8;            \
        f32x4 wlo = *reinterpret_cast<const f32x4*>(wr);                      \
        f32x4 whi = *reinterpret_cast<const f32x4*>(wr + 4);                  \
        unsigned short slb = SLt[(pg * 16 + pix16) * 20 + (KK)];              \
        float sl = __uint_as_float((unsigned)slb << 16);                      \
        float sp = wlo[0] * acc[0][pg][0];                                    \
        sp = fmaf(wlo[1], acc[0][pg][1], sp);                                 \
        sp = fmaf(wlo[2], acc[0][pg][2], sp);                                 \
        sp = fmaf(wlo[3], acc[0][pg][3], sp);                                 \
        sp = fmaf(whi[0], acc[1][pg][0], sp);                                 \
        sp = fmaf(whi[1], acc[1][pg][1], sp);                                 \
        sp = fmaf(whi[2], acc[1][pg][2], sp);                                 \
        sp = fmaf(whi[3], acc[1][pg][3], sp);                                 \
        oreg[pg] = fmaf(acc[2][pg][0], sp, fmaf(sl, acc[2][pg][1], oreg[pg]));\
    }

// ---------------------------------------------------------------------------
// Fused conv-GEMM + KAN epilogue. R17 structure (102 us main, VGPR 120,
// no spill) + chunk-PAIR parity loop: two inlined 9-step bodies; bodyA uses
// pa[r&1] and prefetches pa[(r+1)&1] INCLUDING r==8 (chunk B r0); bodyB uses
// pa[(r+1)&1] and prefetches pa[r&1] (pair step 10+r; at r==8 the next
// pair's r0). Every step keeps loads in flight; chunk B's first frags fly
// across chunk A's epilogue; live set identical to R17 (pa[2][3], all
// indices compile-time). First pa[0] loads issued BEFORE __syncthreads
// (hide under table build). Table epilogue, bias-via-GEMM, cg L2 pinning,
// partials + reduce: all R17-proven, unchanged.
// ---------------------------------------------------------------------------
__global__ void __launch_bounds__(512, 1)
main_kernel(const float* __restrict__ x, const unsigned short* __restrict__ bp3,
            float* __restrict__ dst0, float* __restrict__ dst1,
            int two_cg, int c0_in, int nc_in, int add_in) {
    __shared__ unsigned short slab[3 * 66 * 40];   // 15840 B
    __shared__ float Wt[64 * 132];                 // 33792 B
    __shared__ unsigned short SLt[64 * 20];        // 2560 B
    const int tid = threadIdx.x;
    const int bid = blockIdx.x;
    int row, ch, c0, nc, addf;
    float* dst;
    if (two_cg) {
        int cg = bid & 1;          // XCD = bid%8 -> cg fixed per XCD (L2 pin)
        ch = (bid >> 1) & 1;
        row = bid >> 2;
        c0 = cg ? 16 : 0;
        nc = cg ? 15 : 16;
        dst = cg ? dst1 : dst0;
        addf = 0;
    } else {
        ch = bid & 1; row = bid >> 1;
        c0 = c0_in; nc = nc_in; dst = dst0; addf = add_in;
    }

    // slab: rows row-1..row+1, cols ch*64-1 .. ch*64+64; slot31 = 1.0 (bias col)
    for (int idx = tid; idx < 3 * 66 * 40; idx += 512) {
        int slot = idx % 40;
        int t = idx / 40;
        int cc = t % 66;
        int rr = t / 66;
        int hh = row - 1 + rr, ww = ch * 64 - 1 + cc;
        unsigned short v = 0;
        if (slot < 31) {
            if ((unsigned)hh < 128u && (unsigned)ww < 128u)
                v = f2bf(x[slot * NPIX + hh * 128 + ww]);
        } else if (slot == 31) {
            v = 0x3F80;   // 1.0 bf16
        }
        slab[(rr * 66 + cc) * 40 + slot] = v;
    }

    // spline/silu tables: once per (pixel, chunk), from f32 x (center pixels)
    for (int idx = tid; idx < nc * 64; idx += 512) {
        int px = idx & 63;
        int k = idx >> 6;
        float xv = x[(size_t)(c0 + k) * NPIX + row * 128 + ch * 64 + px];
        float u5 = (xv + 1.0f) * 2.5f;
        float cf = fminf(fmaxf(floorf(u5), 0.f), 4.f);
        int ccb = (int)cf;
        float t = u5 - cf;
        float omt = 1.f - t;
        float t2v = t * t, t3v = t2v * t;
        float bw0 = omt * omt * omt * (1.f / 6.f);
        float bw3 = t3v * (1.f / 6.f);
        float bw1 = 0.5f * t3v - t2v + (2.f / 3.f);
        float bw2 = 1.f - bw0 - bw1 - bw3;         // partition of unity
        float* wr = Wt + px * 132 + k * 8;
        *reinterpret_cast<f32x4*>(wr) = (f32x4){0.f, 0.f, 0.f, 0.f};
        *reinterpret_cast<f32x4*>(wr + 4) = (f32x4){0.f, 0.f, 0.f, 0.f};
        wr[ccb] = bw0; wr[ccb + 1] = bw1; wr[ccb + 2] = bw2; wr[ccb + 3] = bw3;
        SLt[px * 20 + k] = f2bf(xv / (1.f + __expf(-xv)));
    }

    const int lane = tid & 63;
    const int fi = tid >> 6;              // 0..7: this wave's frag triple
    const int q = lane >> 4;
    const int pix16 = lane & 15;
    const char* slabb = (const char*)slab;

    // prologue A-loads (global->reg, no LDS dep): hide under the table build
    s16x8 pa[2][3];
    {
        const unsigned short* aw0 = bp3
            + ((size_t)c0 * NR * NFRG + fi * 3) * FRAG_U16 + lane * 8;
        #pragma unroll
        for (int fl = 0; fl < 3; ++fl)
            pa[0][fl] = *reinterpret_cast<const s16x8*>(aw0 + fl * FRAG_U16);
    }
    __syncthreads();
    // ---- no further barriers; slab/Wt/SLt are read-only below ----

    int sa[4];
    #pragma unroll
    for (int pg = 0; pg < 4; ++pg)
        sa[pg] = (pg * 16 + pix16) * 80 + q * 16;   // slab byte offsets

    float oreg[4] = {0.f, 0.f, 0.f, 0.f};
    f32x4 acc[3][4];

    int kl = 0;
    #pragma unroll 1
    for (; kl + 2 <= nc; kl += 2) {
        const unsigned short* aw = bp3
            + ((size_t)(c0 + kl) * NR * NFRG + fi * 3) * FRAG_U16 + lane * 8;

        // ---- chunk A: uses pa[r&1]; prefetch pa[(r+1)&1] (r==8 -> chunk B r0)
        KAN_ZERO();
        #pragma unroll
        for (int r = 0; r < NR; ++r) {
            #pragma unroll
            for (int fl = 0; fl < 3; ++fl)
                pa[(r + 1) & 1][fl] = *reinterpret_cast<const s16x8*>(
                    aw + (r + 1) * STEP_U16 + fl * FRAG_U16);
            KAN_MFMA(r & 1);
        }
        KAN_EPI(kl);

        // ---- chunk B: uses pa[(r+1)&1]; prefetch pa[r&1] (pair step 10+r;
        //      r==8 -> next pair's chunk-A r0, only if more work remains)
        KAN_ZERO();
        #pragma unroll
        for (int r = 0; r < NR; ++r) {
            if (r < 8 || kl + 2 < nc) {
                const int off = (r < 8) ? (10 + r) : 18;
                #pragma unroll
                for (int fl = 0; fl < 3; ++fl)
                    pa[r & 1][fl] = *reinterpret_cast<const s16x8*>(
                        aw + off * STEP_U16 + fl * FRAG_U16);
            }
            KAN_MFMA((r + 1) & 1);
        }
        KAN_EPI(kl + 1);
    }
    if (kl < nc) {   // odd tail chunk: pa[0] preloaded by last pair's bodyB r8
        const unsigned short* aw = bp3
            + ((size_t)(c0 + kl) * NR * NFRG + fi * 3) * FRAG_U16 + lane * 8;
        KAN_ZERO();
        #pragma unroll
        for (int r = 0; r < NR; ++r) {
            if (r + 1 < NR) {
                #pragma unroll
                for (int fl = 0; fl < 3; ++fl)
                    pa[(r + 1) & 1][fl] = *reinterpret_cast<const s16x8*>(
                        aw + (r + 1) * STEP_U16 + fl * FRAG_U16);
            }
            KAN_MFMA(r & 1);
        }
        KAN_EPI(kl);
    }

    // write: lane's single output channel o = q*8 + fi (o==31 is pad -> skip)
    const int o = q * 8 + fi;
    if (o < OUT_CH) {
        #pragma unroll
        for (int pg = 0; pg < 4; ++pg) {
            size_t gi = (size_t)o * NPIX + row * 128 + ch * 64 + pg * 16 + pix16;
            if (addf) dst[gi] += oreg[pg];
            else      dst[gi]  = oreg[pg];
        }
    }
}

__global__ void reduce_kernel(const float* __restrict__ p1, float* __restrict__ out) {
    int e = blockIdx.x * 256 + threadIdx.x;
    if (e < OUT_CH * NPIX) out[e] += p1[e];
}

extern "C" void kernel_launch(void* const* d_in, const int* in_sizes, int n_in,
                              void* d_out, int out_size, void* d_ws, size_t ws_size,
                              hipStream_t stream) {
    const float* x  = (const float*)d_in[0];   // (1,31,128,128)
    const float* gw = (const float*)d_in[1];   // (9610,31,3,3)
    const float* gb = (const float*)d_in[2];   // (9610,)
    float* outp = (float*)d_out;               // (1,31,128,128)
    unsigned short* bpack = (unsigned short*)d_ws;          // 6,856,704 B
    float* p1 = (float*)((char*)d_ws + BP3_B);

    const int NMAIN = CHUNKS * NFRG * 64;                   // 47616
    pack_kernel<<<(NMAIN + 255) / 256, 256, 0, stream>>>(gw, gb, bpack);

    if (ws_size >= WS_NEED) {
        // 512 blocks = 128 rows x 2 col-halves x 2 cg; cg0 -> out, cg1 -> p1
        main_kernel<<<512, 512, 0, stream>>>(x, bpack, outp, p1, 1, 0, 0, 0);
        reduce_kernel<<<(OUT_CH * NPIX + 255) / 256, 256, 0, stream>>>(p1, outp);
    } else {
        // chained fallback: two sequential dispatches (256 blocks each) through d_out
        main_kernel<<<256, 512, 0, stream>>>(x, bpack, outp, nullptr, 0, 0, 16, 0);
        main_kernel<<<256, 512, 0, stream>>>(x, bpack, outp, nullptr, 0, 16, 15, 1);
    }
}

// Round 19
// 109.144 us; speedup vs baseline: 2.3799x; 2.3799x over previous
//
#include <hip/hip_runtime.h>
#include <hip/hip_bf16.h>

// ---- problem constants ----
#define OUT_CH   31
#define COEF_LEN 7688                 // 31*31*8
#define NPIX     16384                // 128*128
#define CHUNKS   31                   // KAN input channels (independent param groups)
#define NFRG     24                   // param fragments per chunk (384 padded M rows)
#define NR       9                    // K-steps: r = ky*3+kx; k-in-step = conv channel ci
#define FRAG_U16 512                  // u16 per fragment (64 lanes x 8)
#define STEP_U16 (NFRG*FRAG_U16)      // 12288 u16 per (chunk,r) step
#define BP3_B    ((size_t)CHUNKS*NR*STEP_U16*2)        // 6,856,704
#define P1_B     ((size_t)OUT_CH*NPIX*4)               // 2,031,616
#define WS_NEED  (BP3_B + P1_B)                        // 8,888,320

using f32x4 = __attribute__((ext_vector_type(4))) float;
using s16x8 = __attribute__((ext_vector_type(8))) short;

__device__ __forceinline__ unsigned short f2bf(float f) {
    unsigned int u = __float_as_uint(f);
    unsigned int r = (u + 0x7FFFu + ((u >> 16) & 1u)) >> 16;
    return (unsigned short)r;
}

// ---------------------------------------------------------------------------
// Pack gen_w/gen_b into bf16 A-fragment layout (R14-proven, unchanged).
// Bias folded into GEMM: slab slot 31 = 1.0; A[ci=31] at r==4 carries gb[p].
//  bp3[i][r][f][lane][8] bf16.  M-row m = lane&15; k-in-step ci = (lane>>4)*8+jj.
//  param identity: o = (m>>2)*8 + f/3, jslot = (f%3)*4 + (m&3)
//    jslot 0..7 = coef j, 8 = univ, 9 = res, 10..11 = zero pad
// ---------------------------------------------------------------------------
__global__ void pack_kernel(const float* __restrict__ gw, const float* __restrict__ gb,
                            unsigned short* __restrict__ bp) {
    const int NMAIN = CHUNKS * NFRG * 64;          // 47616
    int tt = blockIdx.x * 256 + threadIdx.x;
    if (tt >= NMAIN) return;
    int lane = tt & 63;
    int u = tt >> 6;
    int f = u % NFRG;
    int i = u / NFRG;
    int m = lane & 15, q8 = lane >> 4;
    int o = (m >> 2) * 8 + f / 3;
    int jslot = (f % 3) * 4 + (m & 3);
    int p = -1;
    if (o < OUT_CH && jslot < 10) {
        if (jslot < 8)       p = i * 248 + o * 8 + jslot;
        else if (jslot == 8) p = COEF_LEN + i * 31 + o;
        else                 p = COEF_LEN + 961 + i * 31 + o;
    }
    s16x8 vr[NR];
    #pragma unroll
    for (int r = 0; r < NR; ++r)
        #pragma unroll
        for (int jj = 0; jj < 8; ++jj) vr[r][jj] = 0;
    #pragma unroll
    for (int jj = 0; jj < 8; ++jj) {
        int ci = q8 * 8 + jj;
        if (p >= 0) {
            if (ci < 31) {
                const float* gr = gw + (long)p * 279 + ci * 9;
                #pragma unroll
                for (int r = 0; r < NR; ++r) vr[r][jj] = (short)f2bf(gr[r]);
            } else {
                vr[4][jj] = (short)f2bf(gb[p]);   // bias channel, center tap only
            }
        }
    }
    #pragma unroll
    for (int r = 0; r < NR; ++r)
        *reinterpret_cast<s16x8*>(bp + (((size_t)i * NR + r) * NFRG + f) * FRAG_U16 + lane * 8) = vr[r];
}

// ---------------------------------------------------------------------------
// Fused conv-GEMM + KAN epilogue. R17 verbatim — verified best (109.4 us
// total, 102 us main, VGPR 120, no spill, MfmaUtil 49.5%).
//  - A streams GLOBAL->VGPR, pa[2][3] reg-dbuf, per-chunk loop, one barrier.
//  - Table epilogue: Wt[px][k][8] f32 scattered-spline-weight records
//    (132-f32 px stride -> 2-way bank conflict = free) + SLt bf16 silu,
//    built once per block; epilogue/pg = 2 ds_read_b128 + 1 b16 + 10 fma.
//  - Bias via GEMM (slab slot31 = 1.0 column, packed gb at r==4).
// Grid 512 = 128 rows x 2 ch x 2 cg; cg = bid&1 pins a 3.46 MB param slice
// per XCD L2. Output: cg0 -> out, cg1 -> ws partial (+reduce); chained
// fallback if ws small.
// NOTE (R15/R16/R18 post-mortems): any addition to this live set — loop
// flattening, chunk-pair parity prefetch, >2 waves/SIMD caps — crosses the
// 128-reg cap of 512-thr blocks and costs 2.5x via scratch spill + L2 thrash.
// ---------------------------------------------------------------------------
__global__ void __launch_bounds__(512, 1)
main_kernel(const float* __restrict__ x, const unsigned short* __restrict__ bp3,
            float* __restrict__ dst0, float* __restrict__ dst1,
            int two_cg, int c0_in, int nc_in, int add_in) {
    __shared__ unsigned short slab[3 * 66 * 40];   // 15840 B
    __shared__ float Wt[64 * 132];                 // 33792 B
    __shared__ unsigned short SLt[64 * 20];        // 2560 B
    const int tid = threadIdx.x;
    const int bid = blockIdx.x;
    int row, ch, c0, nc, addf;
    float* dst;
    if (two_cg) {
        int cg = bid & 1;          // XCD = bid%8 -> cg fixed per XCD (L2 pin)
        ch = (bid >> 1) & 1;
        row = bid >> 2;
        c0 = cg ? 16 : 0;
        nc = cg ? 15 : 16;
        dst = cg ? dst1 : dst0;
        addf = 0;
    } else {
        ch = bid & 1; row = bid >> 1;
        c0 = c0_in; nc = nc_in; dst = dst0; addf = add_in;
    }

    // slab: rows row-1..row+1, cols ch*64-1 .. ch*64+64; slot31 = 1.0 (bias col)
    for (int idx = tid; idx < 3 * 66 * 40; idx += 512) {
        int slot = idx % 40;
        int t = idx / 40;
        int cc = t % 66;
        int rr = t / 66;
        int hh = row - 1 + rr, ww = ch * 64 - 1 + cc;
        unsigned short v = 0;
        if (slot < 31) {
            if ((unsigned)hh < 128u && (unsigned)ww < 128u)
                v = f2bf(x[slot * NPIX + hh * 128 + ww]);
        } else if (slot == 31) {
            v = 0x3F80;   // 1.0 bf16
        }
        slab[(rr * 66 + cc) * 40 + slot] = v;
    }

    // spline/silu tables: once per (pixel, chunk), from f32 x (center pixels)
    for (int idx = tid; idx < nc * 64; idx += 512) {
        int px = idx & 63;
        int k = idx >> 6;
        float xv = x[(size_t)(c0 + k) * NPIX + row * 128 + ch * 64 + px];
        float u5 = (xv + 1.0f) * 2.5f;
        float cf = fminf(fmaxf(floorf(u5), 0.f), 4.f);
        int ccb = (int)cf;
        float t = u5 - cf;
        float omt = 1.f - t;
        float t2v = t * t, t3v = t2v * t;
        float bw0 = omt * omt * omt * (1.f / 6.f);
        float bw3 = t3v * (1.f / 6.f);
        float bw1 = 0.5f * t3v - t2v + (2.f / 3.f);
        float bw2 = 1.f - bw0 - bw1 - bw3;         // partition of unity
        float* wr = Wt + px * 132 + k * 8;
        *reinterpret_cast<f32x4*>(wr) = (f32x4){0.f, 0.f, 0.f, 0.f};
        *reinterpret_cast<f32x4*>(wr + 4) = (f32x4){0.f, 0.f, 0.f, 0.f};
        wr[ccb] = bw0; wr[ccb + 1] = bw1; wr[ccb + 2] = bw2; wr[ccb + 3] = bw3;
        SLt[px * 20 + k] = f2bf(xv / (1.f + __expf(-xv)));
    }
    __syncthreads();
    // ---- no further barriers; slab/Wt/SLt are read-only below ----

    const int lane = tid & 63;
    const int fi = tid >> 6;              // 0..7: this wave's frag triple
    const int q = lane >> 4;
    const int pix16 = lane & 15;
    const char* slabb = (const char*)slab;

    int sa[4];
    #pragma unroll
    for (int pg = 0; pg < 4; ++pg)
        sa[pg] = (pg * 16 + pix16) * 80 + q * 16;   // slab byte offsets

    float oreg[4] = {0.f, 0.f, 0.f, 0.f};

    #pragma unroll 1
    for (int k = 0; k < nc; ++k) {
        const unsigned short* aw = bp3
            + ((size_t)(c0 + k) * NR * NFRG + fi * 3) * FRAG_U16 + lane * 8;

        s16x8 pa[2][3];
        #pragma unroll
        for (int fl = 0; fl < 3; ++fl)
            pa[0][fl] = *reinterpret_cast<const s16x8*>(aw + fl * FRAG_U16);

        f32x4 acc[3][4];
        #pragma unroll
        for (int fl = 0; fl < 3; ++fl)
            #pragma unroll
            for (int pg = 0; pg < 4; ++pg)
                acc[fl][pg] = (f32x4){0.f, 0.f, 0.f, 0.f};   // bias comes via GEMM

        #pragma unroll
        for (int r = 0; r < NR; ++r) {
            if (r + 1 < NR) {    // reg-dbuf prefetch; static index (r unrolled)
                #pragma unroll
                for (int fl = 0; fl < 3; ++fl)
                    pa[(r + 1) & 1][fl] = *reinterpret_cast<const s16x8*>(
                        aw + (r + 1) * STEP_U16 + fl * FRAG_U16);
            }
            const int roff = ((r / 3) * 66 + (r % 3)) * 80;
            s16x8 pbv[4];
            #pragma unroll
            for (int pg = 0; pg < 4; ++pg)
                pbv[pg] = *reinterpret_cast<const s16x8*>(slabb + sa[pg] + roff);

            __builtin_amdgcn_s_setprio(1);
            #pragma unroll
            for (int fl = 0; fl < 3; ++fl)
                #pragma unroll
                for (int pg = 0; pg < 4; ++pg)
                    acc[fl][pg] = __builtin_amdgcn_mfma_f32_16x16x32_bf16(
                        pa[r & 1][fl], pbv[pg], acc[fl][pg], 0, 0, 0);
            __builtin_amdgcn_s_setprio(0);
        }

        // table epilogue: 2 b128 + 1 b16 LDS reads + 10 fma per pg
        #pragma unroll
        for (int pg = 0; pg < 4; ++pg) {
            const float* wr = Wt + (pg * 16 + pix16) * 132 + k * 8;
            f32x4 wlo = *reinterpret_cast<const f32x4*>(wr);
            f32x4 whi = *reinterpret_cast<const f32x4*>(wr + 4);
            unsigned short slb = SLt[(pg * 16 + pix16) * 20 + k];
            float sl = __uint_as_float((unsigned)slb << 16);
            float sp = wlo[0] * acc[0][pg][0];
            sp = fmaf(wlo[1], acc[0][pg][1], sp);
            sp = fmaf(wlo[2], acc[0][pg][2], sp);
            sp = fmaf(wlo[3], acc[0][pg][3], sp);
            sp = fmaf(whi[0], acc[1][pg][0], sp);
            sp = fmaf(whi[1], acc[1][pg][1], sp);
            sp = fmaf(whi[2], acc[1][pg][2], sp);
            sp = fmaf(whi[3], acc[1][pg][3], sp);
            oreg[pg] = fmaf(acc[2][pg][0], sp, fmaf(sl, acc[2][pg][1], oreg[pg]));
        }
    }

    // write: lane's single output channel o = q*8 + fi (o==31 is pad -> skip)
    const int o = q * 8 + fi;
    if (o < OUT_CH) {
        #pragma unroll
        for (int pg = 0; pg < 4; ++pg) {
            size_t gi = (size_t)o * NPIX + row * 128 + ch * 64 + pg * 16 + pix16;
            if (addf) dst[gi] += oreg[pg];
            else      dst[gi]  = oreg[pg];
        }
    }
}

__global__ void reduce_kernel(const float* __restrict__ p1, float* __restrict__ out) {
    int e = blockIdx.x * 256 + threadIdx.x;
    if (e < OUT_CH * NPIX) out[e] += p1[e];
}

extern "C" void kernel_launch(void* const* d_in, const int* in_sizes, int n_in,
                              void* d_out, int out_size, void* d_ws, size_t ws_size,
                              hipStream_t stream) {
    const float* x  = (const float*)d_in[0];   // (1,31,128,128)
    const float* gw = (const float*)d_in[1];   // (9610,31,3,3)
    const float* gb = (const float*)d_in[2];   // (9610,)
    float* outp = (float*)d_out;               // (1,31,128,128)
    unsigned short* bpack = (unsigned short*)d_ws;          // 6,856,704 B
    float* p1 = (float*)((char*)d_ws + BP3_B);

    const int NMAIN = CHUNKS * NFRG * 64;                   // 47616
    pack_kernel<<<(NMAIN + 255) / 256, 256, 0, stream>>>(gw, gb, bpack);

    if (ws_size >= WS_NEED) {
        // 512 blocks = 128 rows x 2 col-halves x 2 cg; cg0 -> out, cg1 -> p1
        main_kernel<<<512, 512, 0, stream>>>(x, bpack, outp, p1, 1, 0, 0, 0);
        reduce_kernel<<<(OUT_CH * NPIX + 255) / 256, 256, 0, stream>>>(p1, outp);
    } else {
        // chained fallback: two sequential dispatches (256 blocks each) through d_out
        main_kernel<<<256, 512, 0, stream>>>(x, bpack, outp, nullptr, 0, 0, 16, 0);
        main_kernel<<<256, 512, 0, stream>>>(x, bpack, outp, nullptr, 0, 16, 15, 1);
    }
}

// Round 20
// 107.911 us; speedup vs baseline: 2.4071x; 1.0114x over previous
//
#include <hip/hip_runtime.h>
#include <hip/hip_bf16.h>

// ---- problem constants ----
#define OUT_CH   31
#define COEF_LEN 7688                 // 31*31*8
#define NPIX     16384                // 128*128
#define CHUNKS   31                   // KAN input channels (independent param groups)
#define NFRG     24                   // param fragments per chunk (384 padded M rows)
#define NR       9                    // K-steps: r = ky*3+kx; k-in-step = conv channel ci
#define FRAG_U16 512                  // u16 per fragment (64 lanes x 8)
#define STEP_U16 (NFRG*FRAG_U16)      // 12288 u16 per (chunk,r) step
#define BP3_B    ((size_t)CHUNKS*NR*STEP_U16*2)        // 6,856,704
#define P1_B     ((size_t)OUT_CH*NPIX*4)               // 2,031,616
#define WS_NEED  (BP3_B + P1_B)                        // 8,888,320

// dynamic-LDS layout (103,904 B total; 1 block/CU)
#define SLAB_OFF  0                   // u16 [3][130][40] = 31,200 B
#define WT_OFF    31200               // f32 [128][132]   = 67,584 B
#define SLT_OFF   98784               // u16 [128][20]    =  5,120 B
#define LDS_BYTES 103904

using f32x4 = __attribute__((ext_vector_type(4))) float;
using s16x8 = __attribute__((ext_vector_type(8))) short;

__device__ __forceinline__ unsigned short f2bf(float f) {
    unsigned int u = __float_as_uint(f);
    unsigned int r = (u + 0x7FFFu + ((u >> 16) & 1u)) >> 16;
    return (unsigned short)r;
}

// ---------------------------------------------------------------------------
// Pack gen_w/gen_b into bf16 A-fragment layout (R14-proven, unchanged).
// Bias folded into GEMM: slab slot 31 = 1.0; A[ci=31] at r==4 carries gb[p].
//  bp3[i][r][f][lane][8] bf16.  M-row m = lane&15; k-in-step ci = (lane>>4)*8+jj.
//  param identity: o = (m>>2)*8 + f/3, jslot = (f%3)*4 + (m&3)
//    jslot 0..7 = coef j, 8 = univ, 9 = res, 10..11 = zero pad
// ---------------------------------------------------------------------------
__global__ void pack_kernel(const float* __restrict__ gw, const float* __restrict__ gb,
                            unsigned short* __restrict__ bp) {
    const int NMAIN = CHUNKS * NFRG * 64;          // 47616
    int tt = blockIdx.x * 256 + threadIdx.x;
    if (tt >= NMAIN) return;
    int lane = tt & 63;
    int u = tt >> 6;
    int f = u % NFRG;
    int i = u / NFRG;
    int m = lane & 15, q8 = lane >> 4;
    int o = (m >> 2) * 8 + f / 3;
    int jslot = (f % 3) * 4 + (m & 3);
    int p = -1;
    if (o < OUT_CH && jslot < 10) {
        if (jslot < 8)       p = i * 248 + o * 8 + jslot;
        else if (jslot == 8) p = COEF_LEN + i * 31 + o;
        else                 p = COEF_LEN + 961 + i * 31 + o;
    }
    s16x8 vr[NR];
    #pragma unroll
    for (int r = 0; r < NR; ++r)
        #pragma unroll
        for (int jj = 0; jj < 8; ++jj) vr[r][jj] = 0;
    #pragma unroll
    for (int jj = 0; jj < 8; ++jj) {
        int ci = q8 * 8 + jj;
        if (p >= 0) {
            if (ci < 31) {
                const float* gr = gw + (long)p * 279 + ci * 9;
                #pragma unroll
                for (int r = 0; r < NR; ++r) vr[r][jj] = (short)f2bf(gr[r]);
            } else {
                vr[4][jj] = (short)f2bf(gb[p]);   // bias channel, center tap only
            }
        }
    }
    #pragma unroll
    for (int r = 0; r < NR; ++r)
        *reinterpret_cast<s16x8*>(bp + (((size_t)i * NR + r) * NFRG + f) * FRAG_U16 + lane * 8) = vr[r];
}

// ---------------------------------------------------------------------------
// Fused conv-GEMM + KAN epilogue. R17's per-wave code byte-identical
// (3 frags x 4 pg, pa[2][3] reg-dbuf, table epilogue, VGPR 120 proven),
// restructured to 1024-THREAD BLOCKS = 16 waves = 8 fi x 2 pixel-halves,
// 128 px/block (one full image row):
//  - A L2-traffic HALVED (885 MB): each block reads its cg slice once per
//    128 px; second ph-wave's A reads hit L1/L2.
//  - 4 waves/SIMD (16 waves/CU) vs R17's 2 -> doubled latency hiding.
//  - grid 256 = 128 rows x 2 cg = EXACTLY 1 block/CU, single dispatch round
//    (sidesteps the ~1.7-blocks/CU scheduler behavior seen in R13/R16).
// __launch_bounds__(1024,1): cap 128 regs (4 waves/SIMD x 128 = 512 pool);
// R17's live set measured 120. Dynamic LDS 103.9 KB (slab + Wt + SLt).
// cg = bid&1 pins a 3.46 MB param slice per XCD L2. Output: cg0 -> out,
// cg1 -> ws partial (+reduce); chained 2-dispatch fallback if ws small.
// ---------------------------------------------------------------------------
__global__ void __launch_bounds__(1024, 1)
main_kernel(const float* __restrict__ x, const unsigned short* __restrict__ bp3,
            float* __restrict__ dst0, float* __restrict__ dst1,
            int two_cg, int c0_in, int nc_in, int add_in) {
    extern __shared__ char smem[];
    unsigned short* slab = (unsigned short*)(smem + SLAB_OFF);  // [3][130][40]
    float* Wt = (float*)(smem + WT_OFF);                        // [128][132]
    unsigned short* SLt = (unsigned short*)(smem + SLT_OFF);    // [128][20]

    const int tid = threadIdx.x;
    const int bid = blockIdx.x;
    int row, c0, nc, addf;
    float* dst;
    if (two_cg) {
        int cg = bid & 1;          // XCD = bid%8 -> cg fixed per XCD (L2 pin)
        row = bid >> 1;
        c0 = cg ? 16 : 0;
        nc = cg ? 15 : 16;
        dst = cg ? dst1 : dst0;
        addf = 0;
    } else {
        row = bid;
        c0 = c0_in; nc = nc_in; dst = dst0; addf = add_in;
    }

    // slab: rows row-1..row+1, cols -1..128; slot31 = 1.0 (bias col)
    for (int idx = tid; idx < 3 * 130 * 40; idx += 1024) {
        int slot = idx % 40;
        int t = idx / 40;
        int cc = t % 130;
        int rr = t / 130;
        int hh = row - 1 + rr, ww = cc - 1;
        unsigned short v = 0;
        if (slot < 31) {
            if ((unsigned)hh < 128u && (unsigned)ww < 128u)
                v = f2bf(x[slot * NPIX + hh * 128 + ww]);
        } else if (slot == 31) {
            v = 0x3F80;   // 1.0 bf16
        }
        slab[(rr * 130 + cc) * 40 + slot] = v;
    }

    // spline/silu tables: once per (pixel, chunk), from f32 x (center pixels)
    for (int idx = tid; idx < nc * 128; idx += 1024) {
        int px = idx & 127;
        int k = idx >> 7;
        float xv = x[(size_t)(c0 + k) * NPIX + row * 128 + px];
        float u5 = (xv + 1.0f) * 2.5f;
        float cf = fminf(fmaxf(floorf(u5), 0.f), 4.f);
        int ccb = (int)cf;
        float t = u5 - cf;
        float omt = 1.f - t;
        float t2v = t * t, t3v = t2v * t;
        float bw0 = omt * omt * omt * (1.f / 6.f);
        float bw3 = t3v * (1.f / 6.f);
        float bw1 = 0.5f * t3v - t2v + (2.f / 3.f);
        float bw2 = 1.f - bw0 - bw1 - bw3;         // partition of unity
        float* wr = Wt + px * 132 + k * 8;
        *reinterpret_cast<f32x4*>(wr) = (f32x4){0.f, 0.f, 0.f, 0.f};
        *reinterpret_cast<f32x4*>(wr + 4) = (f32x4){0.f, 0.f, 0.f, 0.f};
        wr[ccb] = bw0; wr[ccb + 1] = bw1; wr[ccb + 2] = bw2; wr[ccb + 3] = bw3;
        SLt[px * 20 + k] = f2bf(xv / (1.f + __expf(-xv)));
    }
    __syncthreads();
    // ---- no further barriers; slab/Wt/SLt are read-only below ----

    const int lane = tid & 63;
    const int w = tid >> 6;               // 0..15
    const int fi = w & 7;                 // frag triple [3fi, 3fi+3)
    const int ph = w >> 3;                // pixel half: cols [64*ph, 64*ph+64)
    const int q = lane >> 4;
    const int pix16 = lane & 15;
    const char* slabb = (const char*)slab;

    int sa[4];
    #pragma unroll
    for (int pg = 0; pg < 4; ++pg)
        sa[pg] = (ph * 64 + pg * 16 + pix16) * 80 + q * 16;   // slab byte offsets

    float oreg[4] = {0.f, 0.f, 0.f, 0.f};

    #pragma unroll 1
    for (int k = 0; k < nc; ++k) {
        const unsigned short* aw = bp3
            + ((size_t)(c0 + k) * NR * NFRG + fi * 3) * FRAG_U16 + lane * 8;

        s16x8 pa[2][3];
        #pragma unroll
        for (int fl = 0; fl < 3; ++fl)
            pa[0][fl] = *reinterpret_cast<const s16x8*>(aw + fl * FRAG_U16);

        f32x4 acc[3][4];
        #pragma unroll
        for (int fl = 0; fl < 3; ++fl)
            #pragma unroll
            for (int pg = 0; pg < 4; ++pg)
                acc[fl][pg] = (f32x4){0.f, 0.f, 0.f, 0.f};   // bias comes via GEMM

        #pragma unroll
        for (int r = 0; r < NR; ++r) {
            if (r + 1 < NR) {    // reg-dbuf prefetch; static index (r unrolled)
                #pragma unroll
                for (int fl = 0; fl < 3; ++fl)
                    pa[(r + 1) & 1][fl] = *reinterpret_cast<const s16x8*>(
                        aw + (r + 1) * STEP_U16 + fl * FRAG_U16);
            }
            const int roff = ((r / 3) * 130 + (r % 3)) * 80;
            s16x8 pbv[4];
            #pragma unroll
            for (int pg = 0; pg < 4; ++pg)
                pbv[pg] = *reinterpret_cast<const s16x8*>(slabb + sa[pg] + roff);

            __builtin_amdgcn_s_setprio(1);
            #pragma unroll
            for (int fl = 0; fl < 3; ++fl)
                #pragma unroll
                for (int pg = 0; pg < 4; ++pg)
                    acc[fl][pg] = __builtin_amdgcn_mfma_f32_16x16x32_bf16(
                        pa[r & 1][fl], pbv[pg], acc[fl][pg], 0, 0, 0);
            __builtin_amdgcn_s_setprio(0);
        }

        // table epilogue: 2 b128 + 1 b16 LDS reads + 10 fma per pg
        #pragma unroll
        for (int pg = 0; pg < 4; ++pg) {
            const int px = ph * 64 + pg * 16 + pix16;
            const float* wr = Wt + px * 132 + k * 8;
            f32x4 wlo = *reinterpret_cast<const f32x4*>(wr);
            f32x4 whi = *reinterpret_cast<const f32x4*>(wr + 4);
            unsigned short slb = SLt[px * 20 + k];
            float sl = __uint_as_float((unsigned)slb << 16);
            float sp = wlo[0] * acc[0][pg][0];
            sp = fmaf(wlo[1], acc[0][pg][1], sp);
            sp = fmaf(wlo[2], acc[0][pg][2], sp);
            sp = fmaf(wlo[3], acc[0][pg][3], sp);
            sp = fmaf(whi[0], acc[1][pg][0], sp);
            sp = fmaf(whi[1], acc[1][pg][1], sp);
            sp = fmaf(whi[2], acc[1][pg][2], sp);
            sp = fmaf(whi[3], acc[1][pg][3], sp);
            oreg[pg] = fmaf(acc[2][pg][0], sp, fmaf(sl, acc[2][pg][1], oreg[pg]));
        }
    }

    // write: lane's single output channel o = q*8 + fi (o==31 is pad -> skip)
    const int o = q * 8 + fi;
    if (o < OUT_CH) {
        #pragma unroll
        for (int pg = 0; pg < 4; ++pg) {
            size_t gi = (size_t)o * NPIX + row * 128 + ph * 64 + pg * 16 + pix16;
            if (addf) dst[gi] += oreg[pg];
            else      dst[gi]  = oreg[pg];
        }
    }
}

__global__ void reduce_kernel(const float* __restrict__ p1, float* __restrict__ out) {
    int e = blockIdx.x * 256 + threadIdx.x;
    if (e < OUT_CH * NPIX) out[e] += p1[e];
}

extern "C" void kernel_launch(void* const* d_in, const int* in_sizes, int n_in,
                              void* d_out, int out_size, void* d_ws, size_t ws_size,
                              hipStream_t stream) {
    const float* x  = (const float*)d_in[0];   // (1,31,128,128)
    const float* gw = (const float*)d_in[1];   // (9610,31,3,3)
    const float* gb = (const float*)d_in[2];   // (9610,)
    float* outp = (float*)d_out;               // (1,31,128,128)
    unsigned short* bpack = (unsigned short*)d_ws;          // 6,856,704 B
    float* p1 = (float*)((char*)d_ws + BP3_B);

    hipFuncSetAttribute((const void*)main_kernel,
                        hipFuncAttributeMaxDynamicSharedMemorySize, LDS_BYTES);

    const int NMAIN = CHUNKS * NFRG * 64;                   // 47616
    pack_kernel<<<(NMAIN + 255) / 256, 256, 0, stream>>>(gw, gb, bpack);

    if (ws_size >= WS_NEED) {
        // 256 blocks = 128 rows x 2 cg (1 block/CU); cg0 -> out, cg1 -> p1
        main_kernel<<<256, 1024, LDS_BYTES, stream>>>(x, bpack, outp, p1, 1, 0, 0, 0);
        reduce_kernel<<<(OUT_CH * NPIX + 255) / 256, 256, 0, stream>>>(p1, outp);
    } else {
        // chained fallback: two sequential dispatches (128 blocks each) through d_out
        main_kernel<<<128, 1024, LDS_BYTES, stream>>>(x, bpack, outp, nullptr, 0, 0, 16, 0);
        main_kernel<<<128, 1024, LDS_BYTES, stream>>>(x, bpack, outp, nullptr, 0, 16, 15, 1);
    }
}